// Round 1
// baseline (65.001 us; speedup 1.0000x reference)
//
#include <hip/hip_runtime.h>

#define B_ROWS 2048
#define C_TOTAL 1000
#define C_LOADED 256
#define NEG_PEN 0.03f

// ws layout: [0:4) float total accumulator, [4:8) int n_valid counter
__global__ void __launch_bounds__(C_LOADED)
rank_loss_kernel(const float* __restrict__ ranks,
                 const int* __restrict__ labels,
                 const int* __restrict__ ids,
                 float* __restrict__ ws_total,
                 int* __restrict__ ws_nvalid) {
    __shared__ float rneg[C_LOADED];   // r if label==0 else -1e30 (masked)
    __shared__ float wave_sums[4];
    __shared__ int anyflag;

    const int b = blockIdx.x;
    const int j = threadIdx.x;

    if (j == 0) anyflag = 0;
    __syncthreads();

    const int c = ids[j];                       // gather index
    const float r = ranks[b * C_TOTAL + c];
    const int lab = labels[b * C_TOTAL + c];

    rneg[j] = (lab == 0) ? r : -1e30f;
    if (lab == 1) anyflag = 1;                  // benign race, all write 1
    __syncthreads();

    // Pivot: positives use their own rank; negatives get +3e30 so every
    // term is hugely negative -> relu==0. Branch-free uniform loop.
    const float rp = (lab == 1) ? r : 3e30f;

    float acc = 0.0f;
#pragma unroll 8
    for (int n = 0; n < C_LOADED; ++n) {
        acc += fmaxf(NEG_PEN + rneg[n] - rp, 0.0f);
    }

    // wave (64-lane) reduction
#pragma unroll
    for (int off = 32; off > 0; off >>= 1) {
        acc += __shfl_down(acc, off, 64);
    }
    const int wave = j >> 6;
    const int lane = j & 63;
    if (lane == 0) wave_sums[wave] = acc;
    __syncthreads();

    if (j == 0) {
        float s = wave_sums[0] + wave_sums[1] + wave_sums[2] + wave_sums[3];
        atomicAdd(ws_total, s);
        if (anyflag) atomicAdd(ws_nvalid, 1);
    }
}

__global__ void finalize_kernel(const float* __restrict__ ws_total,
                                const int* __restrict__ ws_nvalid,
                                float* __restrict__ out) {
    out[0] = ws_total[0] / (float)ws_nvalid[0];
}

extern "C" void kernel_launch(void* const* d_in, const int* in_sizes, int n_in,
                              void* d_out, int out_size, void* d_ws, size_t ws_size,
                              hipStream_t stream) {
    const float* ranks  = (const float*)d_in[0];
    const int*   labels = (const int*)d_in[1];
    const int*   ids    = (const int*)d_in[2];
    float* out = (float*)d_out;

    float* ws_total  = (float*)d_ws;
    int*   ws_nvalid = (int*)((char*)d_ws + 4);

    hipMemsetAsync(d_ws, 0, 8, stream);
    rank_loss_kernel<<<B_ROWS, C_LOADED, 0, stream>>>(ranks, labels, ids,
                                                      ws_total, ws_nvalid);
    finalize_kernel<<<1, 1, 0, stream>>>(ws_total, ws_nvalid, out);
}

// Round 2
// 63.275 us; speedup vs baseline: 1.0273x; 1.0273x over previous
//
#include <hip/hip_runtime.h>

#define B_ROWS 2048
#define C_TOTAL 1000
#define C_LOADED 256
#define NEG_PEN 0.03f

// ws layout: [0:4) float total accumulator, [4:8) int n_valid counter
__global__ void __launch_bounds__(C_LOADED)
rank_loss_kernel(const float* __restrict__ ranks,
                 const int* __restrict__ labels,
                 const int* __restrict__ ids,
                 float* __restrict__ ws_total,
                 int* __restrict__ ws_nvalid) {
    __shared__ float rneg[C_LOADED];     // compacted (r_neg + NEG_PEN), padded to 8
    __shared__ float wave_sums[4];
    __shared__ int wave_base[4];
    __shared__ int ncnt;

    const int b = blockIdx.x;
    const int j = threadIdx.x;
    const int lane = j & 63;
    const int wave = j >> 6;

    if (j == 0) ncnt = 0;
    __syncthreads();

    const int c = ids[j];
    const float r = ranks[b * C_TOTAL + c];
    const int lab = labels[b * C_TOTAL + c];
    const bool isneg = (lab == 0);

    // wave-level compaction of negatives (order doesn't matter for the sum)
    unsigned long long m = __ballot(isneg);
    const int cnt_wave = __popcll(m);
    const int my_pos = __popcll(m & ((1ULL << lane) - 1ULL));
    if (lane == 0) wave_base[wave] = atomicAdd(&ncnt, cnt_wave);
    __syncthreads();

    const int N = ncnt;                   // number of negatives in this row
    const int Npad = (N + 7) & ~7;        // pad to multiple of 8 (<= 256)
    if (isneg) rneg[wave_base[wave] + my_pos] = r + NEG_PEN;
    if (j >= N && j < Npad) rneg[j] = -1e30f;   // pad slots: always give relu==0
    __syncthreads();

    // Positives pivot on their own rank; negatives get +3e30 -> all terms 0.
    const float rp = (lab == 1) ? r : 3e30f;

    float a0 = 0.f, a1 = 0.f, a2 = 0.f, a3 = 0.f;
    float a4 = 0.f, a5 = 0.f, a6 = 0.f, a7 = 0.f;
    const float4* rn4 = (const float4*)rneg;
    const int G = Npad >> 2;              // float4 groups, multiple of 2
    for (int g = 0; g < G; g += 2) {
        float4 x = rn4[g];                // broadcast ds_read_b128
        float4 y = rn4[g + 1];
        a0 += fmaxf(x.x - rp, 0.0f);
        a1 += fmaxf(x.y - rp, 0.0f);
        a2 += fmaxf(x.z - rp, 0.0f);
        a3 += fmaxf(x.w - rp, 0.0f);
        a4 += fmaxf(y.x - rp, 0.0f);
        a5 += fmaxf(y.y - rp, 0.0f);
        a6 += fmaxf(y.z - rp, 0.0f);
        a7 += fmaxf(y.w - rp, 0.0f);
    }
    float acc = ((a0 + a1) + (a2 + a3)) + ((a4 + a5) + (a6 + a7));

    // wave reduction
#pragma unroll
    for (int off = 32; off > 0; off >>= 1) {
        acc += __shfl_down(acc, off, 64);
    }
    if (lane == 0) wave_sums[wave] = acc;
    __syncthreads();

    if (j == 0) {
        float s = (wave_sums[0] + wave_sums[1]) + (wave_sums[2] + wave_sums[3]);
        atomicAdd(ws_total, s);
        if (N < C_LOADED) atomicAdd(ws_nvalid, 1);   // any positive <=> N < 256
    }
}

__global__ void finalize_kernel(const float* __restrict__ ws_total,
                                const int* __restrict__ ws_nvalid,
                                float* __restrict__ out) {
    out[0] = ws_total[0] / (float)ws_nvalid[0];
}

extern "C" void kernel_launch(void* const* d_in, const int* in_sizes, int n_in,
                              void* d_out, int out_size, void* d_ws, size_t ws_size,
                              hipStream_t stream) {
    const float* ranks  = (const float*)d_in[0];
    const int*   labels = (const int*)d_in[1];
    const int*   ids    = (const int*)d_in[2];
    float* out = (float*)d_out;

    float* ws_total  = (float*)d_ws;
    int*   ws_nvalid = (int*)((char*)d_ws + 4);

    hipMemsetAsync(d_ws, 0, 8, stream);
    rank_loss_kernel<<<B_ROWS, C_LOADED, 0, stream>>>(ranks, labels, ids,
                                                      ws_total, ws_nvalid);
    finalize_kernel<<<1, 1, 0, stream>>>(ws_total, ws_nvalid, out);
}